// Round 15
// baseline (267.426 us; speedup 1.0000x reference)
//
#include <hip/hip_runtime.h>
#include <hip/hip_bf16.h>

#define NEG_SLOPE 0.2f
#define LOG2E 1.44269504f
#define G_SHIFT 7
#define GSZ 128          // nodes per bucket
#define CHUNK 4096       // edges per coarse block; also per-bucket region capacity
#define GSTRIDE 136      // ushorts per LDS row (gemm): 272B = 17*16B

typedef __attribute__((ext_vector_type(8))) __bf16 bf16x8;
typedef __attribute__((ext_vector_type(4))) float f32x4;
typedef __attribute__((ext_vector_type(2))) float f32x2;

__device__ __forceinline__ unsigned short f2bf(float f) {
    unsigned u = __float_as_uint(f);
    unsigned r = (u + 0x7fffu + ((u >> 16) & 1u)) >> 16;
    return (unsigned short)r;
}
__device__ __forceinline__ float bflo(unsigned v) { return __uint_as_float(v << 16); }
__device__ __forceinline__ float bfhi(unsigned v) { return __uint_as_float(v & 0xffff0000u); }
__device__ __forceinline__ float bf2f(unsigned short v) {
    return __uint_as_float((unsigned)v << 16);
}

// ---------- W1 transpose + bf16 convert: wtb[c][k] = bf16(W1[k][c]) --------
__global__ __launch_bounds__(128) void wconv_kernel(
    const float* __restrict__ W, unsigned short* __restrict__ wtb) {
    int c = blockIdx.x;
    int k = threadIdx.x;
    wtb[c * 128 + k] = f2bf(W[k * 128 + c]);
}

// ---------- K1: coarse scatter ∪ gemm1 MFMA, Bresenham-interleaved ----------
// (r13-vs-r14 A/B with identical pulls: this pairing wins by ~4 µs.)
__global__ __launch_bounds__(256) void k1_coarse_gemm(
    const int* __restrict__ src, const int* __restrict__ dst,
    int* __restrict__ gcursor, unsigned* __restrict__ inter,
    const float* __restrict__ x, const unsigned short* __restrict__ wtb,
    const float* __restrict__ al, const float* __restrict__ ar,
    unsigned short* __restrict__ featb, float* __restrict__ el,
    float* __restrict__ er,
    int N, int E, int NB, int NCH, int GB) {
    __shared__ __align__(16) unsigned short smem[2 * 128 * GSTRIDE];  // 69,632 B
    const int tid = threadIdx.x;
    const int bid = (int)blockIdx.x;
    const long long tot = (long long)NCH + GB;
    const int cb  = (int)(((long long)bid * NCH) / tot);
    const int cb1 = (int)(((long long)(bid + 1) * NCH) / tot);

    if (cb1 > cb) {
        // ---- coarse-scatter role, chunk cb ----
        int* hist = (int*)smem;                 // 800
        int* lbase = hist + 800;                // 800
        int* gbase = lbase + 800;               // 800
        unsigned* stage = (unsigned*)(gbase + 800);          // 4096
        unsigned short* bstage = (unsigned short*)(stage + CHUNK);  // 4096

        const int e0 = cb * CHUNK;
        const int cnt = min(CHUNK, E - e0);

        for (int i = tid; i < NB; i += 256) hist[i] = 0;
        __syncthreads();

        unsigned pk[16];
        int bb[16];
        unsigned short rk[16];
#pragma unroll
        for (int r = 0; r < 16; ++r) {
            int idx = tid + r * 256;
            if (idx < cnt) {
                int s = src[e0 + idx];
                int d = dst[e0 + idx];
                pk[r] = ((unsigned)s << G_SHIFT) | (unsigned)(d & (GSZ - 1));
                bb[r] = d >> G_SHIFT;
                rk[r] = (unsigned short)atomicAdd(&hist[bb[r]], 1);
            }
        }
        __syncthreads();
        if (tid < 64) {
            int carry = 0;
            for (int i = 0; i < NB; i += 64) {
                int v = (i + tid < NB) ? hist[i + tid] : 0;
                int xv = v;
                for (int o = 1; o < 64; o <<= 1) {
                    int tt = __shfl_up(xv, o, 64);
                    if (tid >= o) xv += tt;
                }
                if (i + tid < NB) lbase[i + tid] = carry + xv - v;
                carry += __shfl(xv, 63, 64);
            }
        }
        __syncthreads();
        for (int i = tid; i < NB; i += 256) {
            int hh = hist[i];
            gbase[i] = (hh > 0) ? (i * CHUNK + atomicAdd(&gcursor[i], hh)) : 0;
        }
        __syncthreads();
#pragma unroll
        for (int r = 0; r < 16; ++r) {
            int idx = tid + r * 256;
            if (idx < cnt) {
                int pos = lbase[bb[r]] + (int)rk[r];
                stage[pos] = pk[r];
                bstage[pos] = (unsigned short)bb[r];
            }
        }
        __syncthreads();
#pragma unroll
        for (int r = 0; r < 16; ++r) {
            int idx = tid + r * 256;
            if (idx < cnt) {
                int b = (int)bstage[idx];
                inter[gbase[b] + (idx - lbase[b])] = stage[idx];
            }
        }
        return;
    }

    // ---- gemm1 role, tile bid - cb ----
    unsigned short (*xs)[GSTRIDE] = (unsigned short(*)[GSTRIDE])smem;
    unsigned short (*ws)[GSTRIDE] = (unsigned short(*)[GSTRIDE])(smem + 128 * GSTRIDE);
    const int t = tid;
    const int m0 = (bid - cb) * 128;
    const int w = t >> 6;
    const int l = t & 63;
    const int lr = l & 15;
    const int lg = l >> 4;

    {
        const uint4* wv = (const uint4*)wtb;   // 2048 x 16B
#pragma unroll
        for (int rr = 0; rr < 8; ++rr) {
            int q = t + 256 * rr;
            int c = q >> 4, kb = q & 15;
            uint4 v = wv[q];
            *((uint4*)&ws[c][kb * 8]) = v;
        }
    }
    {
#pragma unroll
        for (int rr = 0; rr < 16; ++rr) {
            int q = t + 256 * rr;              // 4096 float4
            int row = q >> 5, c4 = q & 31;
            int gm = m0 + row;
            if (gm >= N) gm = N - 1;
            float4 v = *((const float4*)(x + (size_t)gm * 128 + c4 * 4));
            ushort4 o;
            o.x = f2bf(v.x); o.y = f2bf(v.y); o.z = f2bf(v.z); o.w = f2bf(v.w);
            *((ushort4*)&xs[row][c4 * 4]) = o;
        }
    }
    __syncthreads();

    f32x4 acc[2][8];
#pragma unroll
    for (int i = 0; i < 2; ++i)
#pragma unroll
        for (int j = 0; j < 8; ++j) acc[i][j] = (f32x4){0.f, 0.f, 0.f, 0.f};

#pragma unroll
    for (int kk = 0; kk < 4; ++kk) {
        const int k0 = kk * 32 + lg * 8;
        bf16x8 a0 = *((const bf16x8*)&xs[w * 32 + lr][k0]);
        bf16x8 a1 = *((const bf16x8*)&xs[w * 32 + 16 + lr][k0]);
#pragma unroll
        for (int nj = 0; nj < 8; ++nj) {
            bf16x8 bfr = *((const bf16x8*)&ws[nj * 16 + lr][k0]);
            acc[0][nj] = __builtin_amdgcn_mfma_f32_16x16x32_bf16(a0, bfr, acc[0][nj], 0, 0, 0);
            acc[1][nj] = __builtin_amdgcn_mfma_f32_16x16x32_bf16(a1, bfr, acc[1][nj], 0, 0, 0);
        }
    }
    __syncthreads();            // frag reads done; reuse xs for output tile
#pragma unroll
    for (int mi = 0; mi < 2; ++mi)
#pragma unroll
        for (int r = 0; r < 4; ++r) {
            int row = w * 32 + mi * 16 + lg * 4 + r;
#pragma unroll
            for (int nj = 0; nj < 8; ++nj)
                xs[row][nj * 16 + lr] = f2bf(acc[mi][nj][r]);
        }
    __syncthreads();
    {
        int row = t >> 1, half = t & 1;
        int gm = m0 + row;
        if (gm < N) {
            float pl0 = 0.f, pl1 = 0.f, pr0 = 0.f, pr1 = 0.f;
            const unsigned short* xr = &xs[row][half * 64];
            uint4* outp = (uint4*)(featb + (size_t)gm * 128 + half * 64);
#pragma unroll
            for (int b8 = 0; b8 < 8; ++b8) {
                uint4 v = *((const uint4*)(xr + b8 * 8));
                int cbase = half * 64 + b8 * 8;
                float4 a0 = *((const float4*)(al + cbase));
                float4 a1 = *((const float4*)(al + cbase + 4));
                float4 r0 = *((const float4*)(ar + cbase));
                float4 r1 = *((const float4*)(ar + cbase + 4));
                float f0 = bflo(v.x), f1 = bfhi(v.x), f2 = bflo(v.y), f3 = bfhi(v.y);
                float f4 = bflo(v.z), f5 = bfhi(v.z), f6 = bflo(v.w), f7 = bfhi(v.w);
                float sl = f0 * a0.x + f1 * a0.y + f2 * a0.z + f3 * a0.w
                         + f4 * a1.x + f5 * a1.y + f6 * a1.z + f7 * a1.w;
                float sr = f0 * r0.x + f1 * r0.y + f2 * r0.z + f3 * r0.w
                         + f4 * r1.x + f5 * r1.y + f6 * r1.z + f7 * r1.w;
                if (b8 < 4) { pl0 += sl; pr0 += sr; } else { pl1 += sl; pr1 += sr; }
                outp[b8] = v;
            }
            el[gm * 4 + half * 2 + 0] = pl0 * LOG2E;
            el[gm * 4 + half * 2 + 1] = pl1 * LOG2E;
            er[gm * 4 + half * 2 + 0] = pr0 * LOG2E;
            er[gm * 4 + half * 2 + 1] = pr1 * LOG2E;
        }
    }
}

// ---------- fine scatter: per-bucket CSR finalize, two-pass, scratch-free ---
__global__ __launch_bounds__(256) void fine_scatter(
    const unsigned* __restrict__ inter, const int* __restrict__ gcursor,
    int* __restrict__ deg, int* __restrict__ rowptr, int* __restrict__ esrc,
    int N, int NB) {
    __shared__ int h[GSZ];
    __shared__ int lb[GSZ];
    __shared__ int redsum[256];
    const int b = blockIdx.x;
    const int tid = threadIdx.x;
    const int cnt = gcursor[b];
    const unsigned* ep = inter + (size_t)b * CHUNK;

    {
        int s = 0;
        for (int i = tid; i < b; i += 256) s += gcursor[i];
        redsum[tid] = s;
        __syncthreads();
        for (int o = 128; o > 0; o >>= 1) {
            if (tid < o) redsum[tid] += redsum[tid + o];
            __syncthreads();
        }
    }
    const int base = redsum[0];

    if (tid < GSZ) h[tid] = 0;
    __syncthreads();
    for (int idx = tid; idx < cnt; idx += 256)
        atomicAdd(&h[(int)(ep[idx] & (GSZ - 1))], 1);
    __syncthreads();
    if (tid < 64) {
        int carry = 0;
        for (int i = 0; i < GSZ; i += 64) {
            int v = h[i + tid];
            int xv = v;
            for (int o = 1; o < 64; o <<= 1) {
                int tt = __shfl_up(xv, o, 64);
                if (tid >= o) xv += tt;
            }
            lb[i + tid] = carry + xv - v;
            carry += __shfl(xv, 63, 64);
        }
    }
    __syncthreads();
    if (tid < GSZ) {
        int node = b * GSZ + tid;
        if (node < N) {
            deg[node] = h[tid];
            rowptr[node] = base + lb[tid];
        }
        h[tid] = 0;
    }
    __syncthreads();
    int* eb = esrc + base;
    for (int idx = tid; idx < cnt; idx += 256) {
        unsigned ed = ep[idx];
        int l = (int)(ed & (GSZ - 1));
        int rk = atomicAdd(&h[l], 1);
        eb[lb[l] + rk] = (int)(ed >> G_SHIFT);
    }
}

// ---------- layer-1 pull: 16 lanes/node, 16-deep masked batches,
// exp deduplicated 4x: lane (h,dq) computes exp only for edges dq*4..dq*4+3,
// shares via static shuffles (lanes dq=0..3 previously did identical work).
__global__ __launch_bounds__(256) void pull1_kernel(
    const int* __restrict__ rowptr, const int* __restrict__ deg,
    const int* __restrict__ esrc, const float* __restrict__ el,
    const float* __restrict__ er, const unsigned short* __restrict__ featb,
    const float* __restrict__ b,
    const float* __restrict__ W2, const float* __restrict__ al2,
    const float* __restrict__ ar2, unsigned short* __restrict__ feat2b,
    float* __restrict__ el2, float* __restrict__ er2, int N) {
    int tid = blockIdx.x * 256 + threadIdx.x;
    int node = tid >> 4;
    int lane = threadIdx.x & 15;
    if (node >= N) return;
    int h = lane >> 2;           // head 0..3
    int dq = lane & 3;           // 8-feat block within head
    int start = rowptr[node];
    int cnt = deg[node];
    float er_nh = er[node * 4 + h];     // pre-scaled by log2e
    const int* ep = esrc + start;
    const unsigned short* fb = featb + h * 32 + dq * 8;  // 16B per edge

    f32x2 acc2[4];
#pragma unroll
    for (int j = 0; j < 4; ++j) acc2[j] = (f32x2){0.f, 0.f};
    float sumex = 0.f;

    for (int i = 0; i < cnt; i += 16) {
        int s[16];
#pragma unroll
        for (int j = 0; j < 16; ++j) {
            int idx = i + j;
            idx = (idx < cnt) ? idx : (cnt - 1);
            s[j] = ep[idx];
        }
        uint4 u[16];
#pragma unroll
        for (int j = 0; j < 16; ++j) u[j] = *((const uint4*)(fb + (size_t)s[j] * 128));
        // exp phase: 4 edges per lane (was 16, 4x redundant across dq)
        float xq[4];
#pragma unroll
        for (int q = 0; q < 4; ++q) {
            int j = dq * 4 + q;
            float v = el[s[j] * 4 + h] + er_nh;
            v = fmaxf(v, NEG_SLOPE * v);
            xq[q] = (i + j < cnt) ? exp2f(v) : 0.f;
        }
#pragma unroll
        for (int j = 0; j < 16; ++j) {
            // edge j's exp lives in lane (h*4 + (j>>2)) slot (j&3)
            float xx = __shfl(xq[j & 3], (lane & 12) | (j >> 2), 16);
            sumex += xx;
            f32x2 xx2 = (f32x2){xx, xx};
            acc2[0] += xx2 * (f32x2){bflo(u[j].x), bfhi(u[j].x)};
            acc2[1] += xx2 * (f32x2){bflo(u[j].y), bfhi(u[j].y)};
            acc2[2] += xx2 * (f32x2){bflo(u[j].z), bfhi(u[j].z)};
            acc2[3] += xx2 * (f32x2){bflo(u[j].w), bfhi(u[j].w)};
        }
    }

    float inv = 1.f / ((sumex == 0.f) ? 1.f : sumex);
    float4 bb0 = *((const float4*)(b + h * 32 + dq * 8));
    float4 bb1 = *((const float4*)(b + h * 32 + dq * 8 + 4));
    float o[8];
    o[0] = acc2[0].x * inv + bb0.x; o[1] = acc2[0].y * inv + bb0.y;
    o[2] = acc2[1].x * inv + bb0.z; o[3] = acc2[1].y * inv + bb0.w;
    o[4] = acc2[2].x * inv + bb1.x; o[5] = acc2[2].y * inv + bb1.y;
    o[6] = acc2[3].x * inv + bb1.z; o[7] = acc2[3].y * inv + bb1.w;
    // mean over heads (lane = h*4+dq; heads on bits 2-3) + relu
#pragma unroll
    for (int j = 0; j < 8; ++j) {
        o[j] += __shfl_xor(o[j], 4);
        o[j] += __shfl_xor(o[j], 8);
        o[j] = fmaxf(o[j] * 0.25f, 0.f);   // hb[d], d = dq*8 + j
    }
    // fused gemm2: fc[c] = sum_d hb[d]*W2[d][c], c = lane
    int c = lane;
    float fc = 0.f;
#pragma unroll
    for (int q = 0; q < 4; ++q) {
#pragma unroll
        for (int j = 0; j < 8; ++j) {
            float hv = __shfl(o[j], q, 16);     // lane q holds dq=q values
            fc += hv * W2[(q * 8 + j) * 16 + c];
        }
    }
    float pl = fc * al2[c];
    float pr = fc * ar2[c];
    pl += __shfl_xor(pl, 1); pl += __shfl_xor(pl, 2);
    pl += __shfl_xor(pl, 4); pl += __shfl_xor(pl, 8);
    pr += __shfl_xor(pr, 1); pr += __shfl_xor(pr, 2);
    pr += __shfl_xor(pr, 4); pr += __shfl_xor(pr, 8);
    feat2b[(size_t)node * 16 + c] = f2bf(fc);   // bf16 table: 3.2 MB, L2-resident
    if (lane == 0) {
        el2[node] = pl * LOG2E;   // pre-scale for exp2 in pull2
        er2[node] = pr * LOG2E;
    }
}

// ---------- layer-2 pull: 4 lanes/node, full 16-batches + masked tail,
// exp deduplicated 4x via width-4 shuffles.
__global__ __launch_bounds__(128) void pull2_kernel(
    const int* __restrict__ rowptr, const int* __restrict__ deg,
    const int* __restrict__ esrc, const float* __restrict__ el,
    const float* __restrict__ er, const unsigned short* __restrict__ feat2b,
    const float* __restrict__ b, float* __restrict__ outp, int N) {
    int tid = blockIdx.x * 128 + threadIdx.x;
    int node = tid >> 2;
    int d4 = threadIdx.x & 3;
    if (node >= N) return;

    int start = rowptr[node];
    int cnt = deg[node];
    float er_n = er[node];              // pre-scaled by log2e
    const int* ep = esrc + start;
    const unsigned short* fb = feat2b + d4 * 4;   // 8B per edge per lane

    f32x2 acc01 = (f32x2){0.f, 0.f};
    f32x2 acc23 = (f32x2){0.f, 0.f};
    float sumex = 0.f;
    const int nfull = cnt & ~15;
    int i = 0;
    for (; i < nfull; i += 16) {
        int s[16];
#pragma unroll
        for (int j = 0; j < 16; ++j) s[j] = ep[i + j];
        ushort4 ff[16];
#pragma unroll
        for (int j = 0; j < 16; ++j) ff[j] = *((const ushort4*)(fb + (size_t)s[j] * 16));
        float xq[4];
#pragma unroll
        for (int q = 0; q < 4; ++q) {
            int j = d4 * 4 + q;
            float v = el[s[j]] + er_n;
            v = fmaxf(v, NEG_SLOPE * v);
            xq[q] = exp2f(v);
        }
#pragma unroll
        for (int j = 0; j < 16; ++j) {
            float ex = __shfl(xq[j & 3], j >> 2, 4);
            sumex += ex;
            f32x2 ex2 = (f32x2){ex, ex};
            acc01 += ex2 * (f32x2){bf2f(ff[j].x), bf2f(ff[j].y)};
            acc23 += ex2 * (f32x2){bf2f(ff[j].z), bf2f(ff[j].w)};
        }
    }
    if (i < cnt) {
        int s[16];
#pragma unroll
        for (int j = 0; j < 16; ++j) {
            int idx = i + j;
            idx = (idx < cnt) ? idx : (cnt - 1);
            s[j] = ep[idx];
        }
        ushort4 ff[16];
#pragma unroll
        for (int j = 0; j < 16; ++j) ff[j] = *((const ushort4*)(fb + (size_t)s[j] * 16));
        float xq[4];
#pragma unroll
        for (int q = 0; q < 4; ++q) {
            int j = d4 * 4 + q;
            float v = el[s[j]] + er_n;
            v = fmaxf(v, NEG_SLOPE * v);
            xq[q] = (i + j < cnt) ? exp2f(v) : 0.f;
        }
#pragma unroll
        for (int j = 0; j < 16; ++j) {
            float ex = __shfl(xq[j & 3], j >> 2, 4);
            sumex += ex;
            f32x2 ex2 = (f32x2){ex, ex};
            acc01 += ex2 * (f32x2){bf2f(ff[j].x), bf2f(ff[j].y)};
            acc23 += ex2 * (f32x2){bf2f(ff[j].z), bf2f(ff[j].w)};
        }
    }
    float inv = 1.f / ((sumex == 0.f) ? 1.f : sumex);
    float4 bb = *((const float4*)(b + d4 * 4));
    float4 o;
    o.x = acc01.x * inv + bb.x;
    o.y = acc01.y * inv + bb.y;
    o.z = acc23.x * inv + bb.z;
    o.w = acc23.y * inv + bb.w;
    *((float4*)(outp + (size_t)node * 16 + d4 * 4)) = o;
}

extern "C" void kernel_launch(void* const* d_in, const int* in_sizes, int n_in,
                              void* d_out, int out_size, void* d_ws, size_t ws_size,
                              hipStream_t stream) {
    const float* x   = (const float*)d_in[0];
    const int*   src = (const int*)d_in[1];
    const int*   dst = (const int*)d_in[2];
    const float* W1  = (const float*)d_in[3];
    const float* al1 = (const float*)d_in[4];
    const float* ar1 = (const float*)d_in[5];
    const float* b1  = (const float*)d_in[6];
    const float* W2  = (const float*)d_in[7];
    const float* al2 = (const float*)d_in[8];
    const float* ar2 = (const float*)d_in[9];
    const float* b2  = (const float*)d_in[10];

    const int E = in_sizes[1];
    const int N = in_sizes[0] / 128;
    const int H1 = 4, C1 = 128;
    const int D2 = 16;
    const int NB = (N + GSZ - 1) / GSZ;
    const int NCH = (E + CHUNK - 1) / CHUNK;
    const int GB = (N + 127) / 128;

    char* p = (char*)d_ws;
    auto alloc_f = [&](size_t n) { float* q = (float*)p; p += n * sizeof(float); return q; };
    auto alloc_i = [&](size_t n) { int* q = (int*)p; p += n * sizeof(int); return q; };

    unsigned short* feat1b = (unsigned short*)p; p += (size_t)N * C1 * sizeof(unsigned short);
    unsigned short* feat2b = (unsigned short*)p; p += (size_t)N * D2 * sizeof(unsigned short);
    float* el1   = alloc_f((size_t)N * H1);
    float* er1   = alloc_f((size_t)N * H1);
    float* el2   = alloc_f(N);
    float* er2   = alloc_f(N);
    int* deg     = alloc_i(N);
    int* rowptr  = alloc_i(N);
    int* esrc    = alloc_i(E);
    int* gcursor = alloc_i(NB);
    unsigned* inter = (unsigned*)alloc_i((size_t)NB * CHUNK);
    unsigned short* wtb = (unsigned short*)p; p += (size_t)128 * 128 * sizeof(unsigned short);

    const int TB = 256;

    // ---- prep: zero bucket cursors, transpose W1 ----
    hipMemsetAsync(gcursor, 0, (size_t)NB * sizeof(int), stream);
    wconv_kernel<<<128, 128, 0, stream>>>(W1, wtb);

    // ---- K1: coarse scatter ∪ gemm1 (Bresenham-interleaved roles) ----
    k1_coarse_gemm<<<NCH + GB, TB, 0, stream>>>(
        src, dst, gcursor, inter,
        x, wtb, al1, ar1, feat1b, el1, er1,
        N, E, NB, NCH, GB);

    // ---- K2: fine scatter (small LDS, high occupancy) ----
    fine_scatter<<<NB, TB, 0, stream>>>(inter, gcursor, deg, rowptr, esrc, N, NB);

    // ---- layer 1 pull ----
    pull1_kernel<<<(int)(((long long)N * 16 + 255) / 256), TB, 0, stream>>>(
        rowptr, deg, esrc, el1, er1, feat1b, b1,
        W2, al2, ar2, feat2b, el2, er2, N);

    // ---- layer 2 pull ----
    pull2_kernel<<<(int)(((long long)N * 4 + 127) / 128), 128, 0, stream>>>(
        rowptr, deg, esrc, el2, er2, feat2b, b2, (float*)d_out, N);
}

// Round 16
// 244.710 us; speedup vs baseline: 1.0928x; 1.0928x over previous
//
#include <hip/hip_runtime.h>
#include <hip/hip_bf16.h>

#define NEG_SLOPE 0.2f
#define LOG2E 1.44269504f
#define G_SHIFT 7
#define GSZ 128          // nodes per bucket
#define CHUNK 4096       // edges per coarse block; also per-bucket region capacity
#define GSTRIDE 136      // ushorts per LDS row (gemm): 272B = 17*16B

typedef __attribute__((ext_vector_type(8))) __bf16 bf16x8;
typedef __attribute__((ext_vector_type(4))) float f32x4;
typedef __attribute__((ext_vector_type(2))) float f32x2;

__device__ __forceinline__ unsigned short f2bf(float f) {
    unsigned u = __float_as_uint(f);
    unsigned r = (u + 0x7fffu + ((u >> 16) & 1u)) >> 16;
    return (unsigned short)r;
}
__device__ __forceinline__ float bflo(unsigned v) { return __uint_as_float(v << 16); }
__device__ __forceinline__ float bfhi(unsigned v) { return __uint_as_float(v & 0xffff0000u); }
__device__ __forceinline__ float bf2f(unsigned short v) {
    return __uint_as_float((unsigned)v << 16);
}

// ---------- W1 transpose + bf16 convert: wtb[c][k] = bf16(W1[k][c]) --------
__global__ __launch_bounds__(128) void wconv_kernel(
    const float* __restrict__ W, unsigned short* __restrict__ wtb) {
    int c = blockIdx.x;
    int k = threadIdx.x;
    wtb[c * 128 + k] = f2bf(W[k * 128 + c]);
}

// ---------- K1: coarse scatter ∪ gemm1 MFMA, Bresenham-interleaved ----------
// (r13-vs-r14 A/B with identical pulls: this pairing wins by ~4 µs.)
__global__ __launch_bounds__(256) void k1_coarse_gemm(
    const int* __restrict__ src, const int* __restrict__ dst,
    int* __restrict__ gcursor, unsigned* __restrict__ inter,
    const float* __restrict__ x, const unsigned short* __restrict__ wtb,
    const float* __restrict__ al, const float* __restrict__ ar,
    unsigned short* __restrict__ featb, float* __restrict__ el,
    float* __restrict__ er,
    int N, int E, int NB, int NCH, int GB) {
    __shared__ __align__(16) unsigned short smem[2 * 128 * GSTRIDE];  // 69,632 B
    const int tid = threadIdx.x;
    const int bid = (int)blockIdx.x;
    const long long tot = (long long)NCH + GB;
    const int cb  = (int)(((long long)bid * NCH) / tot);
    const int cb1 = (int)(((long long)(bid + 1) * NCH) / tot);

    if (cb1 > cb) {
        // ---- coarse-scatter role, chunk cb ----
        int* hist = (int*)smem;                 // 800
        int* lbase = hist + 800;                // 800
        int* gbase = lbase + 800;               // 800
        unsigned* stage = (unsigned*)(gbase + 800);          // 4096
        unsigned short* bstage = (unsigned short*)(stage + CHUNK);  // 4096

        const int e0 = cb * CHUNK;
        const int cnt = min(CHUNK, E - e0);

        for (int i = tid; i < NB; i += 256) hist[i] = 0;
        __syncthreads();

        unsigned pk[16];
        int bb[16];
        unsigned short rk[16];
#pragma unroll
        for (int r = 0; r < 16; ++r) {
            int idx = tid + r * 256;
            if (idx < cnt) {
                int s = src[e0 + idx];
                int d = dst[e0 + idx];
                pk[r] = ((unsigned)s << G_SHIFT) | (unsigned)(d & (GSZ - 1));
                bb[r] = d >> G_SHIFT;
                rk[r] = (unsigned short)atomicAdd(&hist[bb[r]], 1);
            }
        }
        __syncthreads();
        if (tid < 64) {
            int carry = 0;
            for (int i = 0; i < NB; i += 64) {
                int v = (i + tid < NB) ? hist[i + tid] : 0;
                int xv = v;
                for (int o = 1; o < 64; o <<= 1) {
                    int tt = __shfl_up(xv, o, 64);
                    if (tid >= o) xv += tt;
                }
                if (i + tid < NB) lbase[i + tid] = carry + xv - v;
                carry += __shfl(xv, 63, 64);
            }
        }
        __syncthreads();
        for (int i = tid; i < NB; i += 256) {
            int hh = hist[i];
            gbase[i] = (hh > 0) ? (i * CHUNK + atomicAdd(&gcursor[i], hh)) : 0;
        }
        __syncthreads();
#pragma unroll
        for (int r = 0; r < 16; ++r) {
            int idx = tid + r * 256;
            if (idx < cnt) {
                int pos = lbase[bb[r]] + (int)rk[r];
                stage[pos] = pk[r];
                bstage[pos] = (unsigned short)bb[r];
            }
        }
        __syncthreads();
#pragma unroll
        for (int r = 0; r < 16; ++r) {
            int idx = tid + r * 256;
            if (idx < cnt) {
                int b = (int)bstage[idx];
                inter[gbase[b] + (idx - lbase[b])] = stage[idx];
            }
        }
        return;
    }

    // ---- gemm1 role, tile bid - cb ----
    unsigned short (*xs)[GSTRIDE] = (unsigned short(*)[GSTRIDE])smem;
    unsigned short (*ws)[GSTRIDE] = (unsigned short(*)[GSTRIDE])(smem + 128 * GSTRIDE);
    const int t = tid;
    const int m0 = (bid - cb) * 128;
    const int w = t >> 6;
    const int l = t & 63;
    const int lr = l & 15;
    const int lg = l >> 4;

    {
        const uint4* wv = (const uint4*)wtb;   // 2048 x 16B
#pragma unroll
        for (int rr = 0; rr < 8; ++rr) {
            int q = t + 256 * rr;
            int c = q >> 4, kb = q & 15;
            uint4 v = wv[q];
            *((uint4*)&ws[c][kb * 8]) = v;
        }
    }
    {
#pragma unroll
        for (int rr = 0; rr < 16; ++rr) {
            int q = t + 256 * rr;              // 4096 float4
            int row = q >> 5, c4 = q & 31;
            int gm = m0 + row;
            if (gm >= N) gm = N - 1;
            float4 v = *((const float4*)(x + (size_t)gm * 128 + c4 * 4));
            ushort4 o;
            o.x = f2bf(v.x); o.y = f2bf(v.y); o.z = f2bf(v.z); o.w = f2bf(v.w);
            *((ushort4*)&xs[row][c4 * 4]) = o;
        }
    }
    __syncthreads();

    f32x4 acc[2][8];
#pragma unroll
    for (int i = 0; i < 2; ++i)
#pragma unroll
        for (int j = 0; j < 8; ++j) acc[i][j] = (f32x4){0.f, 0.f, 0.f, 0.f};

#pragma unroll
    for (int kk = 0; kk < 4; ++kk) {
        const int k0 = kk * 32 + lg * 8;
        bf16x8 a0 = *((const bf16x8*)&xs[w * 32 + lr][k0]);
        bf16x8 a1 = *((const bf16x8*)&xs[w * 32 + 16 + lr][k0]);
#pragma unroll
        for (int nj = 0; nj < 8; ++nj) {
            bf16x8 bfr = *((const bf16x8*)&ws[nj * 16 + lr][k0]);
            acc[0][nj] = __builtin_amdgcn_mfma_f32_16x16x32_bf16(a0, bfr, acc[0][nj], 0, 0, 0);
            acc[1][nj] = __builtin_amdgcn_mfma_f32_16x16x32_bf16(a1, bfr, acc[1][nj], 0, 0, 0);
        }
    }
    __syncthreads();            // frag reads done; reuse xs for output tile
#pragma unroll
    for (int mi = 0; mi < 2; ++mi)
#pragma unroll
        for (int r = 0; r < 4; ++r) {
            int row = w * 32 + mi * 16 + lg * 4 + r;
#pragma unroll
            for (int nj = 0; nj < 8; ++nj)
                xs[row][nj * 16 + lr] = f2bf(acc[mi][nj][r]);
        }
    __syncthreads();
    {
        int row = t >> 1, half = t & 1;
        int gm = m0 + row;
        if (gm < N) {
            float pl0 = 0.f, pl1 = 0.f, pr0 = 0.f, pr1 = 0.f;
            const unsigned short* xr = &xs[row][half * 64];
            uint4* outp = (uint4*)(featb + (size_t)gm * 128 + half * 64);
#pragma unroll
            for (int b8 = 0; b8 < 8; ++b8) {
                uint4 v = *((const uint4*)(xr + b8 * 8));
                int cbase = half * 64 + b8 * 8;
                float4 a0 = *((const float4*)(al + cbase));
                float4 a1 = *((const float4*)(al + cbase + 4));
                float4 r0 = *((const float4*)(ar + cbase));
                float4 r1 = *((const float4*)(ar + cbase + 4));
                float f0 = bflo(v.x), f1 = bfhi(v.x), f2 = bflo(v.y), f3 = bfhi(v.y);
                float f4 = bflo(v.z), f5 = bfhi(v.z), f6 = bflo(v.w), f7 = bfhi(v.w);
                float sl = f0 * a0.x + f1 * a0.y + f2 * a0.z + f3 * a0.w
                         + f4 * a1.x + f5 * a1.y + f6 * a1.z + f7 * a1.w;
                float sr = f0 * r0.x + f1 * r0.y + f2 * r0.z + f3 * r0.w
                         + f4 * r1.x + f5 * r1.y + f6 * r1.z + f7 * r1.w;
                if (b8 < 4) { pl0 += sl; pr0 += sr; } else { pl1 += sl; pr1 += sr; }
                outp[b8] = v;
            }
            el[gm * 4 + half * 2 + 0] = pl0 * LOG2E;
            el[gm * 4 + half * 2 + 1] = pl1 * LOG2E;
            er[gm * 4 + half * 2 + 0] = pr0 * LOG2E;
            er[gm * 4 + half * 2 + 1] = pr1 * LOG2E;
        }
    }
}

// ---------- fine scatter: per-bucket CSR finalize, two-pass, scratch-free ---
__global__ __launch_bounds__(256) void fine_scatter(
    const unsigned* __restrict__ inter, const int* __restrict__ gcursor,
    int* __restrict__ deg, int* __restrict__ rowptr, int* __restrict__ esrc,
    int N, int NB) {
    __shared__ int h[GSZ];
    __shared__ int lb[GSZ];
    __shared__ int redsum[256];
    const int b = blockIdx.x;
    const int tid = threadIdx.x;
    const int cnt = gcursor[b];
    const unsigned* ep = inter + (size_t)b * CHUNK;

    {
        int s = 0;
        for (int i = tid; i < b; i += 256) s += gcursor[i];
        redsum[tid] = s;
        __syncthreads();
        for (int o = 128; o > 0; o >>= 1) {
            if (tid < o) redsum[tid] += redsum[tid + o];
            __syncthreads();
        }
    }
    const int base = redsum[0];

    if (tid < GSZ) h[tid] = 0;
    __syncthreads();
    for (int idx = tid; idx < cnt; idx += 256)
        atomicAdd(&h[(int)(ep[idx] & (GSZ - 1))], 1);
    __syncthreads();
    if (tid < 64) {
        int carry = 0;
        for (int i = 0; i < GSZ; i += 64) {
            int v = h[i + tid];
            int xv = v;
            for (int o = 1; o < 64; o <<= 1) {
                int tt = __shfl_up(xv, o, 64);
                if (tid >= o) xv += tt;
            }
            lb[i + tid] = carry + xv - v;
            carry += __shfl(xv, 63, 64);
        }
    }
    __syncthreads();
    if (tid < GSZ) {
        int node = b * GSZ + tid;
        if (node < N) {
            deg[node] = h[tid];
            rowptr[node] = base + lb[tid];
        }
        h[tid] = 0;
    }
    __syncthreads();
    int* eb = esrc + base;
    for (int idx = tid; idx < cnt; idx += 256) {
        unsigned ed = ep[idx];
        int l = (int)(ed & (GSZ - 1));
        int rk = atomicAdd(&h[l], 1);
        eb[lb[l] + rk] = (int)(ed >> G_SHIFT);
    }
}

// ---------- layer-1 pull: 16 lanes/node, all-masked 16-deep batches ---------
// (best measured form: 70.2 µs. NO exp dedup — r15 showed shuffle-sharing
// serializes the ILP-rich inner loop and costs occupancy: 94.8 µs.)
__global__ __launch_bounds__(256) void pull1_kernel(
    const int* __restrict__ rowptr, const int* __restrict__ deg,
    const int* __restrict__ esrc, const float* __restrict__ el,
    const float* __restrict__ er, const unsigned short* __restrict__ featb,
    const float* __restrict__ b,
    const float* __restrict__ W2, const float* __restrict__ al2,
    const float* __restrict__ ar2, unsigned short* __restrict__ feat2b,
    float* __restrict__ el2, float* __restrict__ er2, int N) {
    int tid = blockIdx.x * 256 + threadIdx.x;
    int node = tid >> 4;
    int lane = threadIdx.x & 15;
    if (node >= N) return;
    int h = lane >> 2;           // head 0..3
    int dq = lane & 3;           // 8-feat block within head
    int start = rowptr[node];
    int cnt = deg[node];
    float er_nh = er[node * 4 + h];     // pre-scaled by log2e
    const int* ep = esrc + start;
    const unsigned short* fb = featb + h * 32 + dq * 8;  // 16B per edge

    f32x2 acc2[4];
#pragma unroll
    for (int j = 0; j < 4; ++j) acc2[j] = (f32x2){0.f, 0.f};
    float sumex = 0.f;

    for (int i = 0; i < cnt; i += 16) {
        int s[16];
#pragma unroll
        for (int j = 0; j < 16; ++j) {
            int idx = i + j;
            idx = (idx < cnt) ? idx : (cnt - 1);
            s[j] = ep[idx];
        }
        uint4 u[16];
#pragma unroll
        for (int j = 0; j < 16; ++j) u[j] = *((const uint4*)(fb + (size_t)s[j] * 128));
        float e[16];
#pragma unroll
        for (int j = 0; j < 16; ++j) e[j] = el[s[j] * 4 + h];
#pragma unroll
        for (int j = 0; j < 16; ++j) {
            float v = e[j] + er_nh;
            v = fmaxf(v, NEG_SLOPE * v);
            float xx = (i + j < cnt) ? exp2f(v) : 0.f;  // masked lanes contribute 0
            sumex += xx;
            f32x2 xx2 = (f32x2){xx, xx};
            acc2[0] += xx2 * (f32x2){bflo(u[j].x), bfhi(u[j].x)};
            acc2[1] += xx2 * (f32x2){bflo(u[j].y), bfhi(u[j].y)};
            acc2[2] += xx2 * (f32x2){bflo(u[j].z), bfhi(u[j].z)};
            acc2[3] += xx2 * (f32x2){bflo(u[j].w), bfhi(u[j].w)};
        }
    }

    float inv = 1.f / ((sumex == 0.f) ? 1.f : sumex);
    float4 bb0 = *((const float4*)(b + h * 32 + dq * 8));
    float4 bb1 = *((const float4*)(b + h * 32 + dq * 8 + 4));
    float o[8];
    o[0] = acc2[0].x * inv + bb0.x; o[1] = acc2[0].y * inv + bb0.y;
    o[2] = acc2[1].x * inv + bb0.z; o[3] = acc2[1].y * inv + bb0.w;
    o[4] = acc2[2].x * inv + bb1.x; o[5] = acc2[2].y * inv + bb1.y;
    o[6] = acc2[3].x * inv + bb1.z; o[7] = acc2[3].y * inv + bb1.w;
    // mean over heads (lane = h*4+dq; heads on bits 2-3) + relu
#pragma unroll
    for (int j = 0; j < 8; ++j) {
        o[j] += __shfl_xor(o[j], 4);
        o[j] += __shfl_xor(o[j], 8);
        o[j] = fmaxf(o[j] * 0.25f, 0.f);   // hb[d], d = dq*8 + j
    }
    // fused gemm2: fc[c] = sum_d hb[d]*W2[d][c], c = lane
    int c = lane;
    float fc = 0.f;
#pragma unroll
    for (int q = 0; q < 4; ++q) {
#pragma unroll
        for (int j = 0; j < 8; ++j) {
            float hv = __shfl(o[j], q, 16);     // lane q holds dq=q values
            fc += hv * W2[(q * 8 + j) * 16 + c];
        }
    }
    float pl = fc * al2[c];
    float pr = fc * ar2[c];
    pl += __shfl_xor(pl, 1); pl += __shfl_xor(pl, 2);
    pl += __shfl_xor(pl, 4); pl += __shfl_xor(pl, 8);
    pr += __shfl_xor(pr, 1); pr += __shfl_xor(pr, 2);
    pr += __shfl_xor(pr, 4); pr += __shfl_xor(pr, 8);
    feat2b[(size_t)node * 16 + c] = f2bf(fc);   // bf16 table: 3.2 MB, L2-resident
    if (lane == 0) {
        el2[node] = pl * LOG2E;   // pre-scale for exp2 in pull2
        er2[node] = pr * LOG2E;
    }
}

// ---------- layer-2 pull: 4 lanes/node, full 16-batches + masked tail,
// exp deduplicated 4x via width-4 shuffles (r15: blind −2.6 µs, kept).
__global__ __launch_bounds__(128) void pull2_kernel(
    const int* __restrict__ rowptr, const int* __restrict__ deg,
    const int* __restrict__ esrc, const float* __restrict__ el,
    const float* __restrict__ er, const unsigned short* __restrict__ feat2b,
    const float* __restrict__ b, float* __restrict__ outp, int N) {
    int tid = blockIdx.x * 128 + threadIdx.x;
    int node = tid >> 2;
    int d4 = threadIdx.x & 3;
    if (node >= N) return;

    int start = rowptr[node];
    int cnt = deg[node];
    float er_n = er[node];              // pre-scaled by log2e
    const int* ep = esrc + start;
    const unsigned short* fb = feat2b + d4 * 4;   // 8B per edge per lane

    f32x2 acc01 = (f32x2){0.f, 0.f};
    f32x2 acc23 = (f32x2){0.f, 0.f};
    float sumex = 0.f;
    const int nfull = cnt & ~15;
    int i = 0;
    for (; i < nfull; i += 16) {
        int s[16];
#pragma unroll
        for (int j = 0; j < 16; ++j) s[j] = ep[i + j];
        ushort4 ff[16];
#pragma unroll
        for (int j = 0; j < 16; ++j) ff[j] = *((const ushort4*)(fb + (size_t)s[j] * 16));
        float xq[4];
#pragma unroll
        for (int q = 0; q < 4; ++q) {
            int j = d4 * 4 + q;
            float v = el[s[j]] + er_n;
            v = fmaxf(v, NEG_SLOPE * v);
            xq[q] = exp2f(v);
        }
#pragma unroll
        for (int j = 0; j < 16; ++j) {
            float ex = __shfl(xq[j & 3], j >> 2, 4);
            sumex += ex;
            f32x2 ex2 = (f32x2){ex, ex};
            acc01 += ex2 * (f32x2){bf2f(ff[j].x), bf2f(ff[j].y)};
            acc23 += ex2 * (f32x2){bf2f(ff[j].z), bf2f(ff[j].w)};
        }
    }
    if (i < cnt) {
        int s[16];
#pragma unroll
        for (int j = 0; j < 16; ++j) {
            int idx = i + j;
            idx = (idx < cnt) ? idx : (cnt - 1);
            s[j] = ep[idx];
        }
        ushort4 ff[16];
#pragma unroll
        for (int j = 0; j < 16; ++j) ff[j] = *((const ushort4*)(fb + (size_t)s[j] * 16));
        float xq[4];
#pragma unroll
        for (int q = 0; q < 4; ++q) {
            int j = d4 * 4 + q;
            float v = el[s[j]] + er_n;
            v = fmaxf(v, NEG_SLOPE * v);
            xq[q] = (i + j < cnt) ? exp2f(v) : 0.f;
        }
#pragma unroll
        for (int j = 0; j < 16; ++j) {
            float ex = __shfl(xq[j & 3], j >> 2, 4);
            sumex += ex;
            f32x2 ex2 = (f32x2){ex, ex};
            acc01 += ex2 * (f32x2){bf2f(ff[j].x), bf2f(ff[j].y)};
            acc23 += ex2 * (f32x2){bf2f(ff[j].z), bf2f(ff[j].w)};
        }
    }
    float inv = 1.f / ((sumex == 0.f) ? 1.f : sumex);
    float4 bb = *((const float4*)(b + d4 * 4));
    float4 o;
    o.x = acc01.x * inv + bb.x;
    o.y = acc01.y * inv + bb.y;
    o.z = acc23.x * inv + bb.z;
    o.w = acc23.y * inv + bb.w;
    *((float4*)(outp + (size_t)node * 16 + d4 * 4)) = o;
}

extern "C" void kernel_launch(void* const* d_in, const int* in_sizes, int n_in,
                              void* d_out, int out_size, void* d_ws, size_t ws_size,
                              hipStream_t stream) {
    const float* x   = (const float*)d_in[0];
    const int*   src = (const int*)d_in[1];
    const int*   dst = (const int*)d_in[2];
    const float* W1  = (const float*)d_in[3];
    const float* al1 = (const float*)d_in[4];
    const float* ar1 = (const float*)d_in[5];
    const float* b1  = (const float*)d_in[6];
    const float* W2  = (const float*)d_in[7];
    const float* al2 = (const float*)d_in[8];
    const float* ar2 = (const float*)d_in[9];
    const float* b2  = (const float*)d_in[10];

    const int E = in_sizes[1];
    const int N = in_sizes[0] / 128;
    const int H1 = 4, C1 = 128;
    const int D2 = 16;
    const int NB = (N + GSZ - 1) / GSZ;
    const int NCH = (E + CHUNK - 1) / CHUNK;
    const int GB = (N + 127) / 128;

    char* p = (char*)d_ws;
    auto alloc_f = [&](size_t n) { float* q = (float*)p; p += n * sizeof(float); return q; };
    auto alloc_i = [&](size_t n) { int* q = (int*)p; p += n * sizeof(int); return q; };

    unsigned short* feat1b = (unsigned short*)p; p += (size_t)N * C1 * sizeof(unsigned short);
    unsigned short* feat2b = (unsigned short*)p; p += (size_t)N * D2 * sizeof(unsigned short);
    float* el1   = alloc_f((size_t)N * H1);
    float* er1   = alloc_f((size_t)N * H1);
    float* el2   = alloc_f(N);
    float* er2   = alloc_f(N);
    int* deg     = alloc_i(N);
    int* rowptr  = alloc_i(N);
    int* esrc    = alloc_i(E);
    int* gcursor = alloc_i(NB);
    unsigned* inter = (unsigned*)alloc_i((size_t)NB * CHUNK);
    unsigned short* wtb = (unsigned short*)p; p += (size_t)128 * 128 * sizeof(unsigned short);

    const int TB = 256;

    // ---- prep: zero bucket cursors, transpose W1 ----
    hipMemsetAsync(gcursor, 0, (size_t)NB * sizeof(int), stream);
    wconv_kernel<<<128, 128, 0, stream>>>(W1, wtb);

    // ---- K1: coarse scatter ∪ gemm1 (Bresenham-interleaved roles) ----
    k1_coarse_gemm<<<NCH + GB, TB, 0, stream>>>(
        src, dst, gcursor, inter,
        x, wtb, al1, ar1, feat1b, el1, er1,
        N, E, NB, NCH, GB);

    // ---- K2: fine scatter (small LDS, high occupancy) ----
    fine_scatter<<<NB, TB, 0, stream>>>(inter, gcursor, deg, rowptr, esrc, N, NB);

    // ---- layer 1 pull ----
    pull1_kernel<<<(int)(((long long)N * 16 + 255) / 256), TB, 0, stream>>>(
        rowptr, deg, esrc, el1, er1, feat1b, b1,
        W2, al2, ar2, feat2b, el2, er2, N);

    // ---- layer 2 pull ----
    pull2_kernel<<<(int)(((long long)N * 4 + 127) / 128), 128, 0, stream>>>(
        rowptr, deg, esrc, el2, er2, feat2b, b2, (float*)d_out, N);
}